// Round 1
// baseline (257.278 us; speedup 1.0000x reference)
//
#include <hip/hip_runtime.h>

// ---------------------------------------------------------------------------
// MultiheadAttention (B=2, S=2048, E=1024, H=16, D=64, MAX_DIST=4, causal)
// Full bf16-MFMA pipeline:
//   1. f2bf converts: k,v,q (4M each), Wk,Wv,Wq,Wo (1M each)
//   2. proj3: kh=[bs][e], qh=[bs][e] (*0.125), vt=[e][bs] (transposed V proj)
//   3. flash attention with rel-pos bias -> ao=[bs][e] bf16
//   4. out = ao @ Wo^T -> fp32 d_out
// ---------------------------------------------------------------------------

using short8  = __attribute__((ext_vector_type(8))) short;
using floatx4 = __attribute__((ext_vector_type(4))) float;
using float4v = __attribute__((ext_vector_type(4))) float;
using ushort4v = __attribute__((ext_vector_type(4))) unsigned short;

#define LOG2E 1.4426950408889634f

__device__ __forceinline__ unsigned short f2bf(float f) {
  unsigned u = __float_as_uint(f);
  return (unsigned short)((u + 0x7FFFu + ((u >> 16) & 1u)) >> 16);  // RNE
}
__device__ __forceinline__ float bf2f(unsigned short s) {
  return __uint_as_float(((unsigned)s) << 16);
}
__device__ __forceinline__ void gload_lds16(const void* g, void* l) {
  __builtin_amdgcn_global_load_lds(
      (const __attribute__((address_space(1))) unsigned int*)g,
      (__attribute__((address_space(3))) unsigned int*)l, 16, 0, 0);
}

// --------------------------- fp32 -> bf16 convert ---------------------------
__global__ void f2bf_kern(const float* __restrict__ in,
                          unsigned short* __restrict__ out, int n4) {
  int i = blockIdx.x * 256 + threadIdx.x;
  if (i >= n4) return;
  float4v v = ((const float4v*)in)[i];
  ushort4v o;
  o[0] = f2bf(v[0]); o[1] = f2bf(v[1]); o[2] = f2bf(v[2]); o[3] = f2bf(v[3]);
  ((ushort4v*)out)[i] = o;
}

// ------------------------------ GEMM core (NT) ------------------------------
// C[m][n] = alpha * sum_k A[m][k]*B[n][k].  A: M x K row-major bf16 (K%32==0),
// B: N x K row-major bf16. 128x128 tile, BK=32, 256 threads = 4 waves (2x2).
__device__ __forceinline__ void gemm_core(
    const unsigned short* __restrict__ A, const unsigned short* __restrict__ B,
    void* __restrict__ Cv, int N, int K, int mBase, int nBase, float alpha,
    bool outbf, unsigned short* As, unsigned short* Bs) {
  const int tid = threadIdx.x;
  const int lane = tid & 63;
  const int w = tid >> 6;
  const int wr = w >> 1, wc = w & 1;
  const int lr = lane & 15, lg = lane >> 4;

  floatx4 acc[4][4] = {};

  for (int k0 = 0; k0 < K; k0 += 32) {
#pragma unroll
    for (int i = 0; i < 2; ++i) {
      int idx = i * 256 + tid;
      int row = idx >> 2, c8 = (idx & 3) * 8;
      gload_lds16(A + (size_t)(mBase + row) * K + (k0 + c8), As + idx * 8);
      gload_lds16(B + (size_t)(nBase + row) * K + (k0 + c8), Bs + idx * 8);
    }
    __syncthreads();
    short8 af[4], bfr[4];
#pragma unroll
    for (int mf = 0; mf < 4; ++mf)
      af[mf] = *(const short8*)(As + (wr * 64 + mf * 16 + lr) * 32 + lg * 8);
#pragma unroll
    for (int nf = 0; nf < 4; ++nf)
      bfr[nf] = *(const short8*)(Bs + (wc * 64 + nf * 16 + lr) * 32 + lg * 8);
#pragma unroll
    for (int mf = 0; mf < 4; ++mf)
#pragma unroll
      for (int nf = 0; nf < 4; ++nf)
        acc[mf][nf] = __builtin_amdgcn_mfma_f32_16x16x32_bf16(
            af[mf], bfr[nf], acc[mf][nf], 0, 0, 0);
    __syncthreads();
  }

#pragma unroll
  for (int mf = 0; mf < 4; ++mf)
#pragma unroll
    for (int nf = 0; nf < 4; ++nf)
#pragma unroll
      for (int r = 0; r < 4; ++r) {
        size_t row = (size_t)mBase + wr * 64 + mf * 16 + lg * 4 + r;
        size_t col = (size_t)nBase + wc * 64 + nf * 16 + lr;
        float v = acc[mf][nf][r] * alpha;
        if (outbf)
          ((unsigned short*)Cv)[row * (size_t)N + col] = f2bf(v);
        else
          ((float*)Cv)[row * (size_t)N + col] = v;
      }
}

// Fused 3 projections: z=0 kh, z=1 qh (alpha=0.125), z=2 vt (swapped/transposed)
__global__ __launch_bounds__(256, 2) void proj3_kern(
    const unsigned short* __restrict__ kbf, const unsigned short* __restrict__ wkb,
    unsigned short* __restrict__ khb,
    const unsigned short* __restrict__ qbf, const unsigned short* __restrict__ wqb,
    unsigned short* __restrict__ qhb,
    const unsigned short* __restrict__ vbf, const unsigned short* __restrict__ wvb,
    unsigned short* __restrict__ vtb) {
  __shared__ alignas(16) unsigned short As[128 * 32];
  __shared__ alignas(16) unsigned short Bs[128 * 32];
  int z = blockIdx.z;
  if (z == 0)
    gemm_core(kbf, wkb, khb, 1024, 1024, blockIdx.y * 128, blockIdx.x * 128,
              1.0f, true, As, Bs);
  else if (z == 1)
    gemm_core(qbf, wqb, qhb, 1024, 1024, blockIdx.y * 128, blockIdx.x * 128,
              0.125f, true, As, Bs);
  else  // vt[e][bs] = sum_c Wv[e][c] * v[bs][c]
    gemm_core(wvb, vbf, vtb, 4096, 1024, blockIdx.x * 128, blockIdx.y * 128,
              1.0f, true, As, Bs);
}

__global__ __launch_bounds__(256, 2) void gemm_out_kern(
    const unsigned short* __restrict__ A, const unsigned short* __restrict__ B,
    float* __restrict__ C) {
  __shared__ alignas(16) unsigned short As[128 * 32];
  __shared__ alignas(16) unsigned short Bs[128 * 32];
  gemm_core(A, B, C, 1024, 1024, blockIdx.y * 128, blockIdx.x * 128, 1.0f,
            false, As, Bs);
}

// ------------------------------ flash attention -----------------------------
// grid (32 qtiles, 16 heads, 2 batch), 256 threads = 4 waves, each wave owns
// 16 q rows. QB=64, KB=64, online softmax, rel-pos bias (9 buckets, causal).
__global__ __launch_bounds__(256, 2) void attn_kern(
    const unsigned short* __restrict__ qh,   // [4096][1024], pre-scaled
    const unsigned short* __restrict__ kh,   // [4096][1024]
    const unsigned short* __restrict__ vt,   // [1024][4096]  (vt[e][bs])
    const float* __restrict__ pp,            // [64][9]
    unsigned short* __restrict__ ao) {       // [4096][1024]
  __shared__ alignas(16) unsigned short Qs[64 * 64];
  __shared__ alignas(16) unsigned short Ks[64 * 64];
  __shared__ alignas(16) unsigned short Vs[64 * 64];
  __shared__ alignas(16) unsigned short Ps[4][16 * 64];
  __shared__ float biasS[64 * 12];

  const int tid = threadIdx.x;
  const int lane = tid & 63;
  const int w = tid >> 6;
  const int lr = lane & 15, lg = lane >> 4;
  const int qt = blockIdx.x, h = blockIdx.y, b = blockIdx.z;
  const int qbase = qt * 64;
  const size_t bsQ = (size_t)b * 2048 + qbase;

  // stage Q tile (64 rows x 64 d)
#pragma unroll
  for (int i = 0; i < 2; ++i) {
    int idx = i * 256 + tid;
    int row = idx >> 3, c8 = (idx & 7) * 8;
    gload_lds16(qh + (bsQ + row) * 1024 + h * 64 + c8, Qs + idx * 8);
  }
  __syncthreads();

  // rel-pos bias: biasS[row][r] = sum_d qh[row][d] * p[d][r]
  for (int idx = tid; idx < 64 * 9; idx += 256) {
    int row = idx / 9, r = idx % 9;
    float s = 0.f;
#pragma unroll
    for (int d = 0; d < 64; ++d) s += bf2f(Qs[row * 64 + d]) * pp[d * 9 + r];
    biasS[row * 12 + r] = s;
  }
  __syncthreads();

  // per-wave Q fragments (constant over K tiles)
  short8 aq[2];
#pragma unroll
  for (int c = 0; c < 2; ++c)
    aq[c] = *(const short8*)(Qs + (w * 16 + lr) * 64 + c * 32 + lg * 8);

  const int rowLoc = w * 16 + lg * 4;  // + r
  float b8[4];
#pragma unroll
  for (int r = 0; r < 4; ++r) b8[r] = biasS[(rowLoc + r) * 12 + 8];

  float m_run[4], l_run[4];
  floatx4 o[4] = {};
#pragma unroll
  for (int r = 0; r < 4; ++r) { m_run[r] = -1e30f; l_run[r] = 0.f; }

  for (int kt = 0; kt <= qt; ++kt) {
    const int kbase = kt * 64;
#pragma unroll
    for (int i = 0; i < 2; ++i) {
      int idx = i * 256 + tid;
      int row = idx >> 3, c8 = (idx & 7) * 8;
      gload_lds16(kh + ((size_t)b * 2048 + kbase + row) * 1024 + h * 64 + c8,
                  Ks + idx * 8);
      gload_lds16(vt + ((size_t)h * 64 + row) * 4096 + b * 2048 + kbase + c8,
                  Vs + idx * 8);
    }
    __syncthreads();

    // S = Q @ K^T  (wave: 16 q rows x 64 k cols)
    floatx4 sa[4] = {};
#pragma unroll
    for (int kf = 0; kf < 4; ++kf)
#pragma unroll
      for (int c = 0; c < 2; ++c) {
        short8 bk = *(const short8*)(Ks + (kf * 16 + lr) * 64 + c * 32 + lg * 8);
        sa[kf] = __builtin_amdgcn_mfma_f32_16x16x32_bf16(aq[c], bk, sa[kf], 0, 0, 0);
      }

    // rel bias + causal mask
    if (qbase + w * 16 >= kbase + 67) {  // whole wave-tile has q-k >= 4
#pragma unroll
      for (int kf = 0; kf < 4; ++kf)
#pragma unroll
        for (int r = 0; r < 4; ++r) sa[kf][r] += b8[r];
    } else {
#pragma unroll
      for (int kf = 0; kf < 4; ++kf)
#pragma unroll
        for (int r = 0; r < 4; ++r) {
          int dq = (qbase + rowLoc + r) - (kbase + kf * 16 + lr);
          if (dq < 0)
            sa[kf][r] = -1e30f;
          else
            sa[kf][r] += biasS[(rowLoc + r) * 12 + (dq > 4 ? 8 : dq + 4)];
        }
    }

    // online softmax
    float mx[4], mn[4], al[4], rs[4];
#pragma unroll
    for (int r = 0; r < 4; ++r) {
      mx[r] = fmaxf(fmaxf(sa[0][r], sa[1][r]), fmaxf(sa[2][r], sa[3][r]));
#pragma unroll
      for (int off = 1; off < 16; off <<= 1)
        mx[r] = fmaxf(mx[r], __shfl_xor(mx[r], off, 16));
      mn[r] = fmaxf(m_run[r], mx[r]);
      al[r] = exp2f((m_run[r] - mn[r]) * LOG2E);
      m_run[r] = mn[r];
      rs[r] = 0.f;
    }
#pragma unroll
    for (int kf = 0; kf < 4; ++kf)
#pragma unroll
      for (int r = 0; r < 4; ++r) {
        float pv = exp2f((sa[kf][r] - mn[r]) * LOG2E);
        rs[r] += pv;
        Ps[w][(lg * 4 + r) * 64 + kf * 16 + lr] = f2bf(pv);
      }
#pragma unroll
    for (int r = 0; r < 4; ++r) {
#pragma unroll
      for (int off = 1; off < 16; off <<= 1) rs[r] += __shfl_xor(rs[r], off, 16);
      l_run[r] = l_run[r] * al[r] + rs[r];
    }
#pragma unroll
    for (int df = 0; df < 4; ++df)
#pragma unroll
      for (int r = 0; r < 4; ++r) o[df][r] *= al[r];

    // O += P @ V   (P via per-wave LDS transpose round-trip)
#pragma unroll
    for (int c = 0; c < 2; ++c) {
      short8 pa = *(const short8*)(&Ps[w][lr * 64 + c * 32 + lg * 8]);
#pragma unroll
      for (int df = 0; df < 4; ++df) {
        short8 bv = *(const short8*)(Vs + (df * 16 + lr) * 64 + c * 32 + lg * 8);
        o[df] = __builtin_amdgcn_mfma_f32_16x16x32_bf16(pa, bv, o[df], 0, 0, 0);
      }
    }
    __syncthreads();
  }

  // epilogue: ao[bs][e] bf16
#pragma unroll
  for (int df = 0; df < 4; ++df)
#pragma unroll
    for (int r = 0; r < 4; ++r) {
      float v = o[df][r] / l_run[r];
      ao[(bsQ + rowLoc + r) * 1024 + h * 64 + df * 16 + lr] = f2bf(v);
    }
}

// --------------------------------- launcher ---------------------------------
extern "C" void kernel_launch(void* const* d_in, const int* in_sizes, int n_in,
                              void* d_out, int out_size, void* d_ws,
                              size_t ws_size, hipStream_t stream) {
  const float* k_in = (const float*)d_in[0];
  const float* v_in = (const float*)d_in[1];
  const float* q_in = (const float*)d_in[2];
  const float* Wk = (const float*)d_in[3];
  const float* Wv = (const float*)d_in[4];
  const float* Wq = (const float*)d_in[5];
  const float* Wo = (const float*)d_in[6];
  const float* pp = (const float*)d_in[7];

  const size_t NX = 4096u * 1024u;  // 4M elements
  const size_t NW = 1024u * 1024u;  // 1M elements
  unsigned short* ws = (unsigned short*)d_ws;
  unsigned short* kbf = ws;
  unsigned short* vbf = kbf + NX;
  unsigned short* qbf = vbf + NX;
  unsigned short* wkb = qbf + NX;
  unsigned short* wvb = wkb + NW;
  unsigned short* wqb = wvb + NW;
  unsigned short* wob = wqb + NW;
  unsigned short* khb = wob + NW;
  unsigned short* vtb = khb + NX;
  unsigned short* qhb = vtb + NX;
  unsigned short* aob = qhb + NX;  // total 32M elems = 64 MB

  (void)in_sizes; (void)n_in; (void)out_size; (void)ws_size;

  // converts
  f2bf_kern<<<dim3(4096), dim3(256), 0, stream>>>(k_in, kbf, (int)(NX / 4));
  f2bf_kern<<<dim3(4096), dim3(256), 0, stream>>>(v_in, vbf, (int)(NX / 4));
  f2bf_kern<<<dim3(4096), dim3(256), 0, stream>>>(q_in, qbf, (int)(NX / 4));
  f2bf_kern<<<dim3(1024), dim3(256), 0, stream>>>(Wk, wkb, (int)(NW / 4));
  f2bf_kern<<<dim3(1024), dim3(256), 0, stream>>>(Wv, wvb, (int)(NW / 4));
  f2bf_kern<<<dim3(1024), dim3(256), 0, stream>>>(Wq, wqb, (int)(NW / 4));
  f2bf_kern<<<dim3(1024), dim3(256), 0, stream>>>(Wo, wob, (int)(NW / 4));

  // projections (fused 3 GEMMs)
  proj3_kern<<<dim3(8, 32, 3), dim3(256), 0, stream>>>(
      kbf, wkb, khb, qbf, wqb, qhb, vbf, wvb, vtb);

  // attention
  attn_kern<<<dim3(32, 16, 2), dim3(256), 0, stream>>>(qhb, khb, vtb, pp, aob);

  // output projection -> fp32
  gemm_out_kern<<<dim3(8, 32), dim3(256), 0, stream>>>(aob, wob, (float*)d_out);
}

// Round 2
// 192.320 us; speedup vs baseline: 1.3378x; 1.3378x over previous
//
#include <hip/hip_runtime.h>

// ---------------------------------------------------------------------------
// MultiheadAttention (B=2, S=2048, E=1024, H=16, D=64, MAX_DIST=4, causal)
//   1. f2bf converts
//   2. proj3: kh=[bs][e], qh=[bs][e] (*0.125), vt=[e][bs]
//   3. flash attention v2: swapped QK^T, XOR-swizzled LDS, double-buffered K/V
//   4. out = ao @ Wo^T -> fp32
// ---------------------------------------------------------------------------

using short8  = __attribute__((ext_vector_type(8))) short;
using floatx4 = __attribute__((ext_vector_type(4))) float;
using float4v = __attribute__((ext_vector_type(4))) float;
using ushort4v = __attribute__((ext_vector_type(4))) unsigned short;

#define LOG2E 1.4426950408889634f

__device__ __forceinline__ unsigned short f2bf(float f) {
  unsigned u = __float_as_uint(f);
  return (unsigned short)((u + 0x7FFFu + ((u >> 16) & 1u)) >> 16);  // RNE
}
__device__ __forceinline__ float bf2f(unsigned short s) {
  return __uint_as_float(((unsigned)s) << 16);
}
__device__ __forceinline__ void gload_lds16(const void* g, void* l) {
  __builtin_amdgcn_global_load_lds(
      (const __attribute__((address_space(1))) unsigned int*)g,
      (__attribute__((address_space(3))) unsigned int*)l, 16, 0, 0);
}

// --------------------------- fp32 -> bf16 convert ---------------------------
__global__ void f2bf_kern(const float* __restrict__ in,
                          unsigned short* __restrict__ out, int n4) {
  int i = blockIdx.x * 256 + threadIdx.x;
  if (i >= n4) return;
  float4v v = ((const float4v*)in)[i];
  ushort4v o;
  o[0] = f2bf(v[0]); o[1] = f2bf(v[1]); o[2] = f2bf(v[2]); o[3] = f2bf(v[3]);
  ((ushort4v*)out)[i] = o;
}

// ------------------------------ GEMM core (NT) ------------------------------
__device__ __forceinline__ void gemm_core(
    const unsigned short* __restrict__ A, const unsigned short* __restrict__ B,
    void* __restrict__ Cv, int N, int K, int mBase, int nBase, float alpha,
    bool outbf, unsigned short* As, unsigned short* Bs) {
  const int tid = threadIdx.x;
  const int lane = tid & 63;
  const int w = tid >> 6;
  const int wr = w >> 1, wc = w & 1;
  const int lr = lane & 15, lg = lane >> 4;

  floatx4 acc[4][4] = {};

  for (int k0 = 0; k0 < K; k0 += 32) {
#pragma unroll
    for (int i = 0; i < 2; ++i) {
      int idx = i * 256 + tid;
      int row = idx >> 2, c8 = (idx & 3) * 8;
      gload_lds16(A + (size_t)(mBase + row) * K + (k0 + c8), As + idx * 8);
      gload_lds16(B + (size_t)(nBase + row) * K + (k0 + c8), Bs + idx * 8);
    }
    __syncthreads();
    short8 af[4], bfr[4];
#pragma unroll
    for (int mf = 0; mf < 4; ++mf)
      af[mf] = *(const short8*)(As + (wr * 64 + mf * 16 + lr) * 32 + lg * 8);
#pragma unroll
    for (int nf = 0; nf < 4; ++nf)
      bfr[nf] = *(const short8*)(Bs + (wc * 64 + nf * 16 + lr) * 32 + lg * 8);
#pragma unroll
    for (int mf = 0; mf < 4; ++mf)
#pragma unroll
      for (int nf = 0; nf < 4; ++nf)
        acc[mf][nf] = __builtin_amdgcn_mfma_f32_16x16x32_bf16(
            af[mf], bfr[nf], acc[mf][nf], 0, 0, 0);
    __syncthreads();
  }

#pragma unroll
  for (int mf = 0; mf < 4; ++mf)
#pragma unroll
    for (int nf = 0; nf < 4; ++nf)
#pragma unroll
      for (int r = 0; r < 4; ++r) {
        size_t row = (size_t)mBase + wr * 64 + mf * 16 + lg * 4 + r;
        size_t col = (size_t)nBase + wc * 64 + nf * 16 + lr;
        float v = acc[mf][nf][r] * alpha;
        if (outbf)
          ((unsigned short*)Cv)[row * (size_t)N + col] = f2bf(v);
        else
          ((float*)Cv)[row * (size_t)N + col] = v;
      }
}

__global__ __launch_bounds__(256, 2) void proj3_kern(
    const unsigned short* __restrict__ kbf, const unsigned short* __restrict__ wkb,
    unsigned short* __restrict__ khb,
    const unsigned short* __restrict__ qbf, const unsigned short* __restrict__ wqb,
    unsigned short* __restrict__ qhb,
    const unsigned short* __restrict__ vbf, const unsigned short* __restrict__ wvb,
    unsigned short* __restrict__ vtb) {
  __shared__ alignas(16) unsigned short As[128 * 32];
  __shared__ alignas(16) unsigned short Bs[128 * 32];
  int z = blockIdx.z;
  if (z == 0)
    gemm_core(kbf, wkb, khb, 1024, 1024, blockIdx.y * 128, blockIdx.x * 128,
              1.0f, true, As, Bs);
  else if (z == 1)
    gemm_core(qbf, wqb, qhb, 1024, 1024, blockIdx.y * 128, blockIdx.x * 128,
              0.125f, true, As, Bs);
  else
    gemm_core(wvb, vbf, vtb, 4096, 1024, blockIdx.x * 128, blockIdx.y * 128,
              1.0f, true, As, Bs);
}

__global__ __launch_bounds__(256, 2) void gemm_out_kern(
    const unsigned short* __restrict__ A, const unsigned short* __restrict__ B,
    float* __restrict__ C) {
  __shared__ alignas(16) unsigned short As[128 * 32];
  __shared__ alignas(16) unsigned short Bs[128 * 32];
  gemm_core(A, B, C, 1024, 1024, blockIdx.y * 128, blockIdx.x * 128, 1.0f,
            false, As, Bs);
}

// ---------------------------- flash attention v2 ----------------------------
// Swapped QK^T (S^T in regs: lane q = lane&15, k = kf*16 + lg*4 + r).
// XOR-swizzled Ks/Vs/Ps (phys_chunk = chunk ^ (row&7)); Qs linear.
// Double-buffered K/V staging via global_load_lds with pre-swizzled source.
__global__ __launch_bounds__(256, 4) void attn_kern(
    const unsigned short* __restrict__ qh,   // [4096][1024], pre-scaled
    const unsigned short* __restrict__ kh,   // [4096][1024]
    const unsigned short* __restrict__ vt,   // [1024][4096]
    const float* __restrict__ pp,            // [64][9]
    unsigned short* __restrict__ ao) {       // [4096][1024]
  __shared__ alignas(16) unsigned short Qs[64 * 64];
  __shared__ alignas(16) unsigned short Ks[2][64 * 64];
  __shared__ alignas(16) unsigned short Vs[2][64 * 64];
  __shared__ alignas(16) unsigned short Ps[4][16 * 64];
  __shared__ float biasS[64 * 12];

  const int tid = threadIdx.x;
  const int lane = tid & 63;
  const int w = tid >> 6;
  const int lr = lane & 15, lg = lane >> 4;
  const int qt = 31 - blockIdx.x;  // longest blocks first
  const int h = blockIdx.y, b = blockIdx.z;
  const int qbase = qt * 64;
  const size_t bsQ = (size_t)b * 2048 + qbase;

  auto stage_kv = [&](int kbase, int bufi) {
#pragma unroll
    for (int i = 0; i < 2; ++i) {
      int idx = i * 256 + tid;
      int row = idx >> 3, pc = idx & 7;
      int cl = pc ^ (row & 7);  // pre-swizzled global source
      gload_lds16(kh + ((size_t)b * 2048 + kbase + row) * 1024 + h * 64 + cl * 8,
                  Ks[bufi] + idx * 8);
      gload_lds16(vt + ((size_t)h * 64 + row) * 4096 + b * 2048 + kbase + cl * 8,
                  Vs[bufi] + idx * 8);
    }
  };

  // stage Q (linear) + first K/V tile (swizzled)
#pragma unroll
  for (int i = 0; i < 2; ++i) {
    int idx = i * 256 + tid;
    int row = idx >> 3, c8 = (idx & 7) * 8;
    gload_lds16(qh + (bsQ + row) * 1024 + h * 64 + c8, Qs + idx * 8);
  }
  stage_kv(0, 0);
  __syncthreads();

  // rel-pos bias: biasS[row][r] = sum_d qh_scaled[row][d] * p[d][r]
  for (int idx = tid; idx < 64 * 9; idx += 256) {
    int row = idx / 9, r = idx % 9;
    float s = 0.f;
#pragma unroll
    for (int d = 0; d < 64; ++d) s += bf2f(Qs[row * 64 + d]) * pp[d * 9 + r];
    biasS[row * 12 + r] = s;
  }
  __syncthreads();

  // Q fragments (B-operand): lane holds Q[q = w*16+lr][d = c*32+lg*8+j]
  short8 aq[2];
#pragma unroll
  for (int c = 0; c < 2; ++c)
    aq[c] = *(const short8*)(Qs + (w * 16 + lr) * 64 + c * 32 + lg * 8);

  const int q_glob = qbase + w * 16 + lr;          // this lane's q row
  const float b8 = biasS[(w * 16 + lr) * 12 + 8];  // far-distance bucket

  float m_run = -1e30f, l_run = 0.f;
  floatx4 o[4] = {};

  for (int kt = 0; kt <= qt; ++kt) {
    const int kbase = kt * 64;
    const int cur = kt & 1;
    if (kt < qt) stage_kv(kbase + 64, cur ^ 1);  // prefetch next tile

    // S^T = K @ Q^T : lane holds S[k = kf*16+lg*4+r][q = w*16+lr]
    floatx4 sa[4] = {};
#pragma unroll
    for (int kf = 0; kf < 4; ++kf)
#pragma unroll
      for (int c = 0; c < 2; ++c) {
        int row = kf * 16 + lr;
        short8 ak = *(const short8*)(Ks[cur] + row * 64 +
                                     (((c * 4 + lg) ^ (lr & 7)) * 8));
        sa[kf] = __builtin_amdgcn_mfma_f32_16x16x32_bf16(ak, aq[c], sa[kf], 0, 0, 0);
      }

    // bias + causal mask (per lane: q = q_glob fixed, k varies over regs)
    if (qbase + w * 16 >= kbase + 67) {  // entire wave sub-tile at distance > 4
#pragma unroll
      for (int kf = 0; kf < 4; ++kf)
#pragma unroll
        for (int r = 0; r < 4; ++r) sa[kf][r] += b8;
    } else {
#pragma unroll
      for (int kf = 0; kf < 4; ++kf)
#pragma unroll
        for (int r = 0; r < 4; ++r) {
          int dq = q_glob - (kbase + kf * 16 + lg * 4 + r);
          if (dq < 0)
            sa[kf][r] = -1e30f;
          else
            sa[kf][r] += biasS[(w * 16 + lr) * 12 + (dq > 4 ? 8 : dq + 4)];
        }
    }

    // online softmax (row state lane-local: q = lr-space)
    float mx = sa[0][0];
#pragma unroll
    for (int kf = 0; kf < 4; ++kf)
#pragma unroll
      for (int r = 0; r < 4; ++r) mx = fmaxf(mx, sa[kf][r]);
    mx = fmaxf(mx, __shfl_xor(mx, 16, 64));
    mx = fmaxf(mx, __shfl_xor(mx, 32, 64));
    const float mn = fmaxf(m_run, mx);
    const float al = __builtin_amdgcn_exp2f((m_run - mn) * LOG2E);
    m_run = mn;

    float rs = 0.f;
#pragma unroll
    for (int kf = 0; kf < 4; ++kf) {
      ushort4v pk;
#pragma unroll
      for (int r = 0; r < 4; ++r) {
        float pv = __builtin_amdgcn_exp2f((sa[kf][r] - mn) * LOG2E);
        rs += pv;
        pk[r] = f2bf(pv);
      }
      // write P[q=lr][k = kf*16+lg*4 .. +3] as one b64, swizzled
      int chunk = kf * 2 + (lg >> 1);
      int phys = chunk ^ (lr & 7);
      *(ushort4v*)(Ps[w] + lr * 64 + phys * 8 + (lg & 1) * 4) = pk;
    }
    rs += __shfl_xor(rs, 16, 64);
    rs += __shfl_xor(rs, 32, 64);
    l_run = l_run * al + rs;

    // transport al from lr-space to output space (q = lg*4+r)
    float alo[4];
#pragma unroll
    for (int r = 0; r < 4; ++r) alo[r] = __shfl(al, lg * 4 + r, 64);
#pragma unroll
    for (int df = 0; df < 4; ++df)
#pragma unroll
      for (int r = 0; r < 4; ++r) o[df][r] *= alo[r];

    // O += P @ V
#pragma unroll
    for (int c = 0; c < 2; ++c) {
      short8 pa = *(const short8*)(Ps[w] + lr * 64 +
                                   (((c * 4 + lg) ^ (lr & 7)) * 8));
#pragma unroll
      for (int df = 0; df < 4; ++df) {
        int row = df * 16 + lr;
        short8 bv = *(const short8*)(Vs[cur] + row * 64 +
                                     (((c * 4 + lg) ^ (lr & 7)) * 8));
        o[df] = __builtin_amdgcn_mfma_f32_16x16x32_bf16(pa, bv, o[df], 0, 0, 0);
      }
    }
    __syncthreads();  // drains prefetch vmem + guards buffer swap
  }

  // epilogue: lane holds O[q = w*16+lg*4+r][d = df*16+lr]
  float lo[4];
#pragma unroll
  for (int r = 0; r < 4; ++r) lo[r] = __shfl(l_run, lg * 4 + r, 64);
#pragma unroll
  for (int df = 0; df < 4; ++df)
#pragma unroll
    for (int r = 0; r < 4; ++r) {
      float v = o[df][r] / lo[r];
      ao[(bsQ + w * 16 + lg * 4 + r) * 1024 + h * 64 + df * 16 + lr] = f2bf(v);
    }
}

// --------------------------------- launcher ---------------------------------
extern "C" void kernel_launch(void* const* d_in, const int* in_sizes, int n_in,
                              void* d_out, int out_size, void* d_ws,
                              size_t ws_size, hipStream_t stream) {
  const float* k_in = (const float*)d_in[0];
  const float* v_in = (const float*)d_in[1];
  const float* q_in = (const float*)d_in[2];
  const float* Wk = (const float*)d_in[3];
  const float* Wv = (const float*)d_in[4];
  const float* Wq = (const float*)d_in[5];
  const float* Wo = (const float*)d_in[6];
  const float* pp = (const float*)d_in[7];

  const size_t NX = 4096u * 1024u;
  const size_t NW = 1024u * 1024u;
  unsigned short* ws = (unsigned short*)d_ws;
  unsigned short* kbf = ws;
  unsigned short* vbf = kbf + NX;
  unsigned short* qbf = vbf + NX;
  unsigned short* wkb = qbf + NX;
  unsigned short* wvb = wkb + NW;
  unsigned short* wqb = wvb + NW;
  unsigned short* wob = wqb + NW;
  unsigned short* khb = wob + NW;
  unsigned short* vtb = khb + NX;
  unsigned short* qhb = vtb + NX;
  unsigned short* aob = qhb + NX;

  (void)in_sizes; (void)n_in; (void)out_size; (void)ws_size;

  f2bf_kern<<<dim3(4096), dim3(256), 0, stream>>>(k_in, kbf, (int)(NX / 4));
  f2bf_kern<<<dim3(4096), dim3(256), 0, stream>>>(v_in, vbf, (int)(NX / 4));
  f2bf_kern<<<dim3(4096), dim3(256), 0, stream>>>(q_in, qbf, (int)(NX / 4));
  f2bf_kern<<<dim3(1024), dim3(256), 0, stream>>>(Wk, wkb, (int)(NW / 4));
  f2bf_kern<<<dim3(1024), dim3(256), 0, stream>>>(Wv, wvb, (int)(NW / 4));
  f2bf_kern<<<dim3(1024), dim3(256), 0, stream>>>(Wq, wqb, (int)(NW / 4));
  f2bf_kern<<<dim3(1024), dim3(256), 0, stream>>>(Wo, wob, (int)(NW / 4));

  proj3_kern<<<dim3(8, 32, 3), dim3(256), 0, stream>>>(
      kbf, wkb, khb, qbf, wqb, qhb, vbf, wvb, vtb);

  attn_kern<<<dim3(32, 16, 2), dim3(256), 0, stream>>>(qhb, khb, vtb, pp, aob);

  gemm_out_kern<<<dim3(8, 32), dim3(256), 0, stream>>>(aob, wob, (float*)d_out);
}

// Round 4
// 142.092 us; speedup vs baseline: 1.8106x; 1.3535x over previous
//
#include <hip/hip_runtime.h>

// ---------------------------------------------------------------------------
// MultiheadAttention (B=2, S=2048, E=1024, H=16, D=64, MAX_DIST=4, causal)
//   1. f2bf converts
//   2. proj3: kh=[bs][e], qh=[bs][e] (*0.125), vt=[e][bs]
//   3. flash attention v3: paired q-tiles (8 waves), swapped QK^T, XOR-swizzle,
//      double-buffered shared K/V, defer-max, cvt_pk P-pack, setprio
//   4. out = ao @ Wo^T -> fp32
// ---------------------------------------------------------------------------

using short8  = __attribute__((ext_vector_type(8))) short;
using floatx4 = __attribute__((ext_vector_type(4))) float;
using float4v = __attribute__((ext_vector_type(4))) float;
using ushort4v = __attribute__((ext_vector_type(4))) unsigned short;
using uint2v  = __attribute__((ext_vector_type(2))) unsigned int;

#define LOG2E 1.4426950408889634f

__device__ __forceinline__ unsigned short f2bf(float f) {
  unsigned u = __float_as_uint(f);
  return (unsigned short)((u + 0x7FFFu + ((u >> 16) & 1u)) >> 16);  // RNE
}
__device__ __forceinline__ float bf2f(unsigned short s) {
  return __uint_as_float(((unsigned)s) << 16);
}
__device__ __forceinline__ unsigned cvt_pk_bf16(float lo, float hi) {
  unsigned r;
  asm("v_cvt_pk_bf16_f32 %0, %1, %2" : "=v"(r) : "v"(lo), "v"(hi));
  return r;
}
__device__ __forceinline__ void gload_lds16(const void* g, void* l) {
  __builtin_amdgcn_global_load_lds(
      (const __attribute__((address_space(1))) unsigned int*)g,
      (__attribute__((address_space(3))) unsigned int*)l, 16, 0, 0);
}

// --------------------------- fp32 -> bf16 convert ---------------------------
__global__ void f2bf_kern(const float* __restrict__ in,
                          unsigned short* __restrict__ out, int n4) {
  int i = blockIdx.x * 256 + threadIdx.x;
  if (i >= n4) return;
  float4v v = ((const float4v*)in)[i];
  ushort4v o;
  o[0] = f2bf(v[0]); o[1] = f2bf(v[1]); o[2] = f2bf(v[2]); o[3] = f2bf(v[3]);
  ((ushort4v*)out)[i] = o;
}

// ------------------------------ GEMM core (NT) ------------------------------
__device__ __forceinline__ void gemm_core(
    const unsigned short* __restrict__ A, const unsigned short* __restrict__ B,
    void* __restrict__ Cv, int N, int K, int mBase, int nBase, float alpha,
    bool outbf, unsigned short* As, unsigned short* Bs) {
  const int tid = threadIdx.x;
  const int lane = tid & 63;
  const int w = tid >> 6;
  const int wr = w >> 1, wc = w & 1;
  const int lr = lane & 15, lg = lane >> 4;

  floatx4 acc[4][4] = {};

  for (int k0 = 0; k0 < K; k0 += 32) {
#pragma unroll
    for (int i = 0; i < 2; ++i) {
      int idx = i * 256 + tid;
      int row = idx >> 2, c8 = (idx & 3) * 8;
      gload_lds16(A + (size_t)(mBase + row) * K + (k0 + c8), As + idx * 8);
      gload_lds16(B + (size_t)(nBase + row) * K + (k0 + c8), Bs + idx * 8);
    }
    __syncthreads();
    short8 af[4], bfr[4];
#pragma unroll
    for (int mf = 0; mf < 4; ++mf)
      af[mf] = *(const short8*)(As + (wr * 64 + mf * 16 + lr) * 32 + lg * 8);
#pragma unroll
    for (int nf = 0; nf < 4; ++nf)
      bfr[nf] = *(const short8*)(Bs + (wc * 64 + nf * 16 + lr) * 32 + lg * 8);
#pragma unroll
    for (int mf = 0; mf < 4; ++mf)
#pragma unroll
      for (int nf = 0; nf < 4; ++nf)
        acc[mf][nf] = __builtin_amdgcn_mfma_f32_16x16x32_bf16(
            af[mf], bfr[nf], acc[mf][nf], 0, 0, 0);
    __syncthreads();
  }

#pragma unroll
  for (int mf = 0; mf < 4; ++mf)
#pragma unroll
    for (int nf = 0; nf < 4; ++nf)
#pragma unroll
      for (int r = 0; r < 4; ++r) {
        size_t row = (size_t)mBase + wr * 64 + mf * 16 + lg * 4 + r;
        size_t col = (size_t)nBase + wc * 64 + nf * 16 + lr;
        float v = acc[mf][nf][r] * alpha;
        if (outbf)
          ((unsigned short*)Cv)[row * (size_t)N + col] = f2bf(v);
        else
          ((float*)Cv)[row * (size_t)N + col] = v;
      }
}

__global__ __launch_bounds__(256, 2) void proj3_kern(
    const unsigned short* __restrict__ kbf, const unsigned short* __restrict__ wkb,
    unsigned short* __restrict__ khb,
    const unsigned short* __restrict__ qbf, const unsigned short* __restrict__ wqb,
    unsigned short* __restrict__ qhb,
    const unsigned short* __restrict__ vbf, const unsigned short* __restrict__ wvb,
    unsigned short* __restrict__ vtb) {
  __shared__ alignas(16) unsigned short As[128 * 32];
  __shared__ alignas(16) unsigned short Bs[128 * 32];
  int z = blockIdx.z;
  if (z == 0)
    gemm_core(kbf, wkb, khb, 1024, 1024, blockIdx.y * 128, blockIdx.x * 128,
              1.0f, true, As, Bs);
  else if (z == 1)
    gemm_core(qbf, wqb, qhb, 1024, 1024, blockIdx.y * 128, blockIdx.x * 128,
              0.125f, true, As, Bs);
  else
    gemm_core(wvb, vbf, vtb, 4096, 1024, blockIdx.x * 128, blockIdx.y * 128,
              1.0f, true, As, Bs);
}

__global__ __launch_bounds__(256, 2) void gemm_out_kern(
    const unsigned short* __restrict__ A, const unsigned short* __restrict__ B,
    float* __restrict__ C) {
  __shared__ alignas(16) unsigned short As[128 * 32];
  __shared__ alignas(16) unsigned short Bs[128 * 32];
  gemm_core(A, B, C, 1024, 1024, blockIdx.y * 128, blockIdx.x * 128, 1.0f,
            false, As, Bs);
}

// ---------------------------- flash attention v3 ----------------------------
// 8 waves/block. Waves 0-3 own q-tile qtA = blockIdx.x (0..15); waves 4-7 own
// qtB = 31 - qtA. K/V tiles staged ONCE per block (shared common prefix),
// double-buffered, XOR-swizzled. Swapped QK^T: lane's q = wl*16 + (lane&15).
__global__ __launch_bounds__(512, 4) void attn_kern(
    const unsigned short* __restrict__ qh,   // [4096][1024], pre-scaled
    const unsigned short* __restrict__ kh,   // [4096][1024]
    const unsigned short* __restrict__ vt,   // [1024][4096]
    const float* __restrict__ pp,            // [64][9]
    unsigned short* __restrict__ ao) {       // [4096][1024]
  __shared__ alignas(16) unsigned short Qs[128 * 64];
  __shared__ alignas(16) unsigned short Ks[2][64 * 64];
  __shared__ alignas(16) unsigned short Vs[2][64 * 64];
  __shared__ alignas(16) unsigned short Ps[8][16 * 64];
  __shared__ float biasS[128 * 12];
  __shared__ float ppS[9 * 64];  // transposed: ppS[r][d]

  const int tid = threadIdx.x;
  const int lane = tid & 63;
  const int w = tid >> 6;        // 0..7
  const int half = w >> 2;       // 0 -> qtA, 1 -> qtB
  const int wl = w & 3;
  const int lr = lane & 15, lg = lane >> 4;
  const int qtA = blockIdx.x;    // 0..15
  const int qtB = 31 - qtA;      // 16..31
  const int myQt = half ? qtB : qtA;
  const int qbase = myQt * 64;
  const int h = blockIdx.y, b = blockIdx.z;

  const unsigned short* khB = kh + ((size_t)b * 2048) * 1024 + h * 64;
  const unsigned short* vtB = vt + ((size_t)h * 64) * 4096 + b * 2048;

  auto stage_kv = [&](int kbase, int bufi) {
    int row = tid >> 3, pc = tid & 7;
    int cl = pc ^ (row & 7);  // pre-swizzled global source
    gload_lds16(khB + ((kbase + row) << 10) + cl * 8, Ks[bufi] + tid * 8);
    gload_lds16(vtB + (row << 12) + kbase + cl * 8, Vs[bufi] + tid * 8);
  };

  // stage Q (two tiles, linear) + pp table + first K/V tile
#pragma unroll
  for (int i = 0; i < 2; ++i) {
    int idx = i * 512 + tid;
    int row = idx >> 3, c8 = (idx & 7) * 8;
    int srcRow = (row < 64) ? (qtA * 64 + row) : (qtB * 64 + row - 64);
    gload_lds16(qh + ((size_t)b * 2048 + srcRow) * 1024 + h * 64 + c8,
                Qs + idx * 8);
  }
  for (int idx = tid; idx < 576; idx += 512) {  // ALL 9 rows (incl. r=8!)
    int r = idx >> 6, d = idx & 63;
    ppS[r * 64 + d] = pp[d * 9 + r];
  }
  stage_kv(0, 0);
  __syncthreads();

  // rel-pos bias: biasS[row][r] = sum_d qh_scaled[row][d] * p[d][r]
  for (int idx = tid; idx < 128 * 9; idx += 512) {
    int row = idx / 9, r = idx - row * 9;
    const unsigned short* qrow = Qs + row * 64;
    const float* pr = ppS + r * 64;
    float s = 0.f;
#pragma unroll
    for (int d8 = 0; d8 < 8; ++d8) {
      short8 qv = *(const short8*)(qrow + d8 * 8);
#pragma unroll
      for (int j = 0; j < 8; ++j)
        s += bf2f((unsigned short)qv[j]) * pr[d8 * 8 + j];
    }
    biasS[row * 12 + r] = s;
  }
  __syncthreads();

  // Q fragments (B-operand): lane holds Q[q = wl*16+lr][d = c*32+lg*8+j]
  const int qrowL = half * 64 + wl * 16 + lr;  // local Qs/bias row
  short8 aq[2];
#pragma unroll
  for (int c = 0; c < 2; ++c)
    aq[c] = *(const short8*)(Qs + qrowL * 64 + c * 32 + lg * 8);

  const int q_glob = qbase + wl * 16 + lr;
  const float b8 = biasS[qrowL * 12 + 8];  // far-distance bucket bias

  float m_run = -1e30f, l_run = 0.f;
  floatx4 o[4] = {};

  for (int kt = 0; kt <= qtB; ++kt) {
    const int kbase = kt * 64;
    const int cur = kt & 1;
    if (kt < qtB) stage_kv(kbase + 64, cur ^ 1);  // prefetch next (all waves)

    if (kt <= myQt) {
      // S^T = K @ Q^T : lane holds S[k = kf*16+lg*4+r][q = wl*16+lr]
      floatx4 sa[4] = {};
      __builtin_amdgcn_s_setprio(1);
#pragma unroll
      for (int kf = 0; kf < 4; ++kf)
#pragma unroll
        for (int c = 0; c < 2; ++c) {
          int row = kf * 16 + lr;
          short8 ak = *(const short8*)(Ks[cur] + row * 64 +
                                       (((c * 4 + lg) ^ (lr & 7)) * 8));
          sa[kf] = __builtin_amdgcn_mfma_f32_16x16x32_bf16(ak, aq[c], sa[kf],
                                                           0, 0, 0);
        }
      __builtin_amdgcn_s_setprio(0);

      // bias + causal mask
      float bext;
      if (qbase + wl * 16 >= kbase + 67) {  // whole wave sub-tile at dist >= 4
        bext = b8;                          // folded into exp arg below
      } else {
        bext = 0.f;
#pragma unroll
        for (int kf = 0; kf < 4; ++kf)
#pragma unroll
          for (int r = 0; r < 4; ++r) {
            int dq = q_glob - (kbase + kf * 16 + lg * 4 + r);
            if (dq < 0)
              sa[kf][r] = -1e30f;
            else
              sa[kf][r] += biasS[qrowL * 12 + (dq > 4 ? 8 : dq + 4)];
          }
      }

      // online softmax with defer-max (THR=8)
      float mx = -1e30f;
#pragma unroll
      for (int kf = 0; kf < 4; ++kf)
#pragma unroll
        for (int r = 0; r < 4; ++r) mx = fmaxf(mx, sa[kf][r]);
      mx += bext;
      mx = fmaxf(mx, __shfl_xor(mx, 16, 64));
      mx = fmaxf(mx, __shfl_xor(mx, 32, 64));
      if (__any(mx > m_run + 8.f)) {
        float mn = fmaxf(m_run, mx);
        float al = __builtin_amdgcn_exp2f((m_run - mn) * LOG2E);
        m_run = mn;
        l_run *= al;
        float alo[4];
#pragma unroll
        for (int r = 0; r < 4; ++r) alo[r] = __shfl(al, lg * 4 + r, 64);
#pragma unroll
        for (int df = 0; df < 4; ++df)
#pragma unroll
          for (int r = 0; r < 4; ++r) o[df][r] *= alo[r];
      }

      const float c1 = (bext - m_run) * LOG2E;
      float rs = 0.f;
#pragma unroll
      for (int kf = 0; kf < 4; ++kf) {
        float p0 = __builtin_amdgcn_exp2f(fmaf(sa[kf][0], LOG2E, c1));
        float p1 = __builtin_amdgcn_exp2f(fmaf(sa[kf][1], LOG2E, c1));
        float p2 = __builtin_amdgcn_exp2f(fmaf(sa[kf][2], LOG2E, c1));
        float p3 = __builtin_amdgcn_exp2f(fmaf(sa[kf][3], LOG2E, c1));
        rs += (p0 + p1) + (p2 + p3);
        uint2v pk;
        pk[0] = cvt_pk_bf16(p0, p1);
        pk[1] = cvt_pk_bf16(p2, p3);
        int phys = (kf * 2 + (lg >> 1)) ^ (lr & 7);
        *(uint2v*)(Ps[w] + lr * 64 + phys * 8 + (lg & 1) * 4) = pk;
      }
      rs += __shfl_xor(rs, 16, 64);
      rs += __shfl_xor(rs, 32, 64);
      l_run += rs;

      // O += P @ V
      __builtin_amdgcn_s_setprio(1);
#pragma unroll
      for (int c = 0; c < 2; ++c) {
        short8 pa = *(const short8*)(Ps[w] + lr * 64 +
                                     (((c * 4 + lg) ^ (lr & 7)) * 8));
#pragma unroll
        for (int df = 0; df < 4; ++df) {
          int row = df * 16 + lr;
          short8 bv = *(const short8*)(Vs[cur] + row * 64 +
                                       (((c * 4 + lg) ^ (lr & 7)) * 8));
          o[df] = __builtin_amdgcn_mfma_f32_16x16x32_bf16(pa, bv, o[df],
                                                          0, 0, 0);
        }
      }
      __builtin_amdgcn_s_setprio(0);
    }
    __syncthreads();  // drains prefetch vmem + guards buffer swap
  }

  // epilogue: lane holds O[q = wl*16+lg*4+r][d = df*16+lr]
  float rl[4];
#pragma unroll
  for (int r = 0; r < 4; ++r)
    rl[r] = __builtin_amdgcn_rcpf(__shfl(l_run, lg * 4 + r, 64));
  const size_t outRow0 = (size_t)b * 2048 + qbase + wl * 16 + lg * 4;
#pragma unroll
  for (int df = 0; df < 4; ++df)
#pragma unroll
    for (int r = 0; r < 4; ++r) {
      float v = o[df][r] * rl[r];
      ao[(outRow0 + r) * 1024 + h * 64 + df * 16 + lr] = f2bf(v);
    }
}

// --------------------------------- launcher ---------------------------------
extern "C" void kernel_launch(void* const* d_in, const int* in_sizes, int n_in,
                              void* d_out, int out_size, void* d_ws,
                              size_t ws_size, hipStream_t stream) {
  const float* k_in = (const float*)d_in[0];
  const float* v_in = (const float*)d_in[1];
  const float* q_in = (const float*)d_in[2];
  const float* Wk = (const float*)d_in[3];
  const float* Wv = (const float*)d_in[4];
  const float* Wq = (const float*)d_in[5];
  const float* Wo = (const float*)d_in[6];
  const float* pp = (const float*)d_in[7];

  const size_t NX = 4096u * 1024u;
  const size_t NW = 1024u * 1024u;
  unsigned short* ws = (unsigned short*)d_ws;
  unsigned short* kbf = ws;
  unsigned short* vbf = kbf + NX;
  unsigned short* qbf = vbf + NX;
  unsigned short* wkb = qbf + NX;
  unsigned short* wvb = wkb + NW;
  unsigned short* wqb = wvb + NW;
  unsigned short* wob = wqb + NW;
  unsigned short* khb = wob + NW;
  unsigned short* vtb = khb + NX;
  unsigned short* qhb = vtb + NX;
  unsigned short* aob = qhb + NX;

  (void)in_sizes; (void)n_in; (void)out_size; (void)ws_size;

  f2bf_kern<<<dim3(4096), dim3(256), 0, stream>>>(k_in, kbf, (int)(NX / 4));
  f2bf_kern<<<dim3(4096), dim3(256), 0, stream>>>(v_in, vbf, (int)(NX / 4));
  f2bf_kern<<<dim3(4096), dim3(256), 0, stream>>>(q_in, qbf, (int)(NX / 4));
  f2bf_kern<<<dim3(1024), dim3(256), 0, stream>>>(Wk, wkb, (int)(NW / 4));
  f2bf_kern<<<dim3(1024), dim3(256), 0, stream>>>(Wv, wvb, (int)(NW / 4));
  f2bf_kern<<<dim3(1024), dim3(256), 0, stream>>>(Wq, wqb, (int)(NW / 4));
  f2bf_kern<<<dim3(1024), dim3(256), 0, stream>>>(Wo, wob, (int)(NW / 4));

  proj3_kern<<<dim3(8, 32, 3), dim3(256), 0, stream>>>(
      kbf, wkb, khb, qbf, wqb, qhb, vbf, wvb, vtb);

  attn_kern<<<dim3(16, 16, 2), dim3(512), 0, stream>>>(qhb, khb, vtb, pp, aob);

  gemm_out_kern<<<dim3(8, 32), dim3(256), 0, stream>>>(aob, wob, (float*)d_out);
}

// Round 5
// 134.463 us; speedup vs baseline: 1.9134x; 1.0567x over previous
//
#include <hip/hip_runtime.h>

// ---------------------------------------------------------------------------
// MultiheadAttention (B=2, S=2048, E=1024, H=16, D=64, MAX_DIST=4, causal)
//   1. f2bf converts (x once -- k,v,q identical; 4 weights fused)
//   2. proj3: kh=[bs][e], qh=[bs][e] (*0.125), vt=[e][bs]
//   3. flash attention v4: ADJACENT paired q-tiles (2i,2i+1), longest-first,
//      swapped QK^T, XOR-swizzle, double-buffered shared K/V, defer-max,
//      cvt_pk P-pack, setprio
//   4. out = ao @ Wo^T -> fp32
// ---------------------------------------------------------------------------

using short8  = __attribute__((ext_vector_type(8))) short;
using floatx4 = __attribute__((ext_vector_type(4))) float;
using float4v = __attribute__((ext_vector_type(4))) float;
using ushort4v = __attribute__((ext_vector_type(4))) unsigned short;
using uint2v  = __attribute__((ext_vector_type(2))) unsigned int;

#define LOG2E 1.4426950408889634f

__device__ __forceinline__ unsigned short f2bf(float f) {
  unsigned u = __float_as_uint(f);
  return (unsigned short)((u + 0x7FFFu + ((u >> 16) & 1u)) >> 16);  // RNE
}
__device__ __forceinline__ float bf2f(unsigned short s) {
  return __uint_as_float(((unsigned)s) << 16);
}
__device__ __forceinline__ unsigned cvt_pk_bf16(float lo, float hi) {
  unsigned r;
  asm("v_cvt_pk_bf16_f32 %0, %1, %2" : "=v"(r) : "v"(lo), "v"(hi));
  return r;
}
__device__ __forceinline__ void gload_lds16(const void* g, void* l) {
  __builtin_amdgcn_global_load_lds(
      (const __attribute__((address_space(1))) unsigned int*)g,
      (__attribute__((address_space(3))) unsigned int*)l, 16, 0, 0);
}

// --------------------------- fp32 -> bf16 convert ---------------------------
__global__ void f2bf_kern(const float* __restrict__ in,
                          unsigned short* __restrict__ out, int n4) {
  int i = blockIdx.x * 256 + threadIdx.x;
  if (i >= n4) return;
  float4v v = ((const float4v*)in)[i];
  ushort4v o;
  o[0] = f2bf(v[0]); o[1] = f2bf(v[1]); o[2] = f2bf(v[2]); o[3] = f2bf(v[3]);
  ((ushort4v*)out)[i] = o;
}

// 4 weight matrices (1M elems each) in one kernel: blockIdx.y selects.
__global__ void f2bfW_kern(const float* __restrict__ w0, unsigned short* o0,
                           const float* __restrict__ w1, unsigned short* o1,
                           const float* __restrict__ w2, unsigned short* o2,
                           const float* __restrict__ w3, unsigned short* o3) {
  int i = blockIdx.x * 256 + threadIdx.x;  // 0 .. 256K-1 (x4 floats)
  const float* in;
  unsigned short* out;
  switch (blockIdx.y) {
    case 0: in = w0; out = o0; break;
    case 1: in = w1; out = o1; break;
    case 2: in = w2; out = o2; break;
    default: in = w3; out = o3; break;
  }
  float4v v = ((const float4v*)in)[i];
  ushort4v o;
  o[0] = f2bf(v[0]); o[1] = f2bf(v[1]); o[2] = f2bf(v[2]); o[3] = f2bf(v[3]);
  ((ushort4v*)out)[i] = o;
}

// ------------------------------ GEMM core (NT) ------------------------------
__device__ __forceinline__ void gemm_core(
    const unsigned short* __restrict__ A, const unsigned short* __restrict__ B,
    void* __restrict__ Cv, int N, int K, int mBase, int nBase, float alpha,
    bool outbf, unsigned short* As, unsigned short* Bs) {
  const int tid = threadIdx.x;
  const int lane = tid & 63;
  const int w = tid >> 6;
  const int wr = w >> 1, wc = w & 1;
  const int lr = lane & 15, lg = lane >> 4;

  floatx4 acc[4][4] = {};

  for (int k0 = 0; k0 < K; k0 += 32) {
#pragma unroll
    for (int i = 0; i < 2; ++i) {
      int idx = i * 256 + tid;
      int row = idx >> 2, c8 = (idx & 3) * 8;
      gload_lds16(A + (size_t)(mBase + row) * K + (k0 + c8), As + idx * 8);
      gload_lds16(B + (size_t)(nBase + row) * K + (k0 + c8), Bs + idx * 8);
    }
    __syncthreads();
    short8 af[4], bfr[4];
#pragma unroll
    for (int mf = 0; mf < 4; ++mf)
      af[mf] = *(const short8*)(As + (wr * 64 + mf * 16 + lr) * 32 + lg * 8);
#pragma unroll
    for (int nf = 0; nf < 4; ++nf)
      bfr[nf] = *(const short8*)(Bs + (wc * 64 + nf * 16 + lr) * 32 + lg * 8);
#pragma unroll
    for (int mf = 0; mf < 4; ++mf)
#pragma unroll
      for (int nf = 0; nf < 4; ++nf)
        acc[mf][nf] = __builtin_amdgcn_mfma_f32_16x16x32_bf16(
            af[mf], bfr[nf], acc[mf][nf], 0, 0, 0);
    __syncthreads();
  }

#pragma unroll
  for (int mf = 0; mf < 4; ++mf)
#pragma unroll
    for (int nf = 0; nf < 4; ++nf)
#pragma unroll
      for (int r = 0; r < 4; ++r) {
        size_t row = (size_t)mBase + wr * 64 + mf * 16 + lg * 4 + r;
        size_t col = (size_t)nBase + wc * 64 + nf * 16 + lr;
        float v = acc[mf][nf][r] * alpha;
        if (outbf)
          ((unsigned short*)Cv)[row * (size_t)N + col] = f2bf(v);
        else
          ((float*)Cv)[row * (size_t)N + col] = v;
      }
}

__global__ __launch_bounds__(256, 2) void proj3_kern(
    const unsigned short* __restrict__ xbf, const unsigned short* __restrict__ wkb,
    unsigned short* __restrict__ khb,
    const unsigned short* __restrict__ wqb, unsigned short* __restrict__ qhb,
    const unsigned short* __restrict__ wvb, unsigned short* __restrict__ vtb) {
  __shared__ alignas(16) unsigned short As[128 * 32];
  __shared__ alignas(16) unsigned short Bs[128 * 32];
  int z = blockIdx.z;
  if (z == 0)
    gemm_core(xbf, wkb, khb, 1024, 1024, blockIdx.y * 128, blockIdx.x * 128,
              1.0f, true, As, Bs);
  else if (z == 1)
    gemm_core(xbf, wqb, qhb, 1024, 1024, blockIdx.y * 128, blockIdx.x * 128,
              0.125f, true, As, Bs);
  else
    gemm_core(wvb, xbf, vtb, 4096, 1024, blockIdx.x * 128, blockIdx.y * 128,
              1.0f, true, As, Bs);
}

__global__ __launch_bounds__(256, 2) void gemm_out_kern(
    const unsigned short* __restrict__ A, const unsigned short* __restrict__ B,
    float* __restrict__ C) {
  __shared__ alignas(16) unsigned short As[128 * 32];
  __shared__ alignas(16) unsigned short Bs[128 * 32];
  gemm_core(A, B, C, 1024, 1024, blockIdx.y * 128, blockIdx.x * 128, 1.0f,
            false, As, Bs);
}

// ---------------------------- flash attention v4 ----------------------------
// 8 waves/block. Pair index i = 15 - blockIdx.x (longest first). Waves 0-3 own
// q-tile qtA = 2i, waves 4-7 own qtB = 2i+1. K/V tiles staged ONCE per block,
// double-buffered, XOR-swizzled. Swapped QK^T: lane's q = wl*16 + (lane&15).
// Adjacent pairing keeps ~97% of wave-steps active (vs ~70% for (i,31-i)).
__global__ __launch_bounds__(512, 4) void attn_kern(
    const unsigned short* __restrict__ qh,   // [4096][1024], pre-scaled
    const unsigned short* __restrict__ kh,   // [4096][1024]
    const unsigned short* __restrict__ vt,   // [1024][4096]
    const float* __restrict__ pp,            // [64][9]
    unsigned short* __restrict__ ao) {       // [4096][1024]
  __shared__ alignas(16) unsigned short Qs[128 * 64];
  __shared__ alignas(16) unsigned short Ks[2][64 * 64];
  __shared__ alignas(16) unsigned short Vs[2][64 * 64];
  __shared__ alignas(16) unsigned short Ps[8][16 * 64];
  __shared__ float biasS[128 * 12];
  __shared__ float ppS[9 * 64];  // transposed: ppS[r][d]

  const int tid = threadIdx.x;
  const int lane = tid & 63;
  const int w = tid >> 6;        // 0..7
  const int half = w >> 2;       // 0 -> qtA, 1 -> qtB
  const int wl = w & 3;
  const int lr = lane & 15, lg = lane >> 4;
  const int pi = 15 - blockIdx.x;  // pair index, longest first
  const int qtA = 2 * pi;
  const int qtB = 2 * pi + 1;
  const int myQt = half ? qtB : qtA;
  const int qbase = myQt * 64;
  const int h = blockIdx.y, b = blockIdx.z;

  const unsigned short* khB = kh + ((size_t)b * 2048) * 1024 + h * 64;
  const unsigned short* vtB = vt + ((size_t)h * 64) * 4096 + b * 2048;

  auto stage_kv = [&](int kbase, int bufi) {
    int row = tid >> 3, pc = tid & 7;
    int cl = pc ^ (row & 7);  // pre-swizzled global source
    gload_lds16(khB + ((kbase + row) << 10) + cl * 8, Ks[bufi] + tid * 8);
    gload_lds16(vtB + (row << 12) + kbase + cl * 8, Vs[bufi] + tid * 8);
  };

  // stage Q (two ADJACENT tiles = 128 contiguous rows) + pp + first K/V tile
#pragma unroll
  for (int i = 0; i < 2; ++i) {
    int idx = i * 512 + tid;
    int row = idx >> 3, c8 = (idx & 7) * 8;
    gload_lds16(qh + ((size_t)b * 2048 + qtA * 64 + row) * 1024 + h * 64 + c8,
                Qs + idx * 8);
  }
  for (int idx = tid; idx < 576; idx += 512) {  // ALL 9 rows (incl. r=8)
    int r = idx >> 6, d = idx & 63;
    ppS[r * 64 + d] = pp[d * 9 + r];
  }
  stage_kv(0, 0);
  __syncthreads();

  // rel-pos bias: biasS[row][r] = sum_d qh_scaled[row][d] * p[d][r]
  for (int idx = tid; idx < 128 * 9; idx += 512) {
    int row = idx / 9, r = idx - row * 9;
    const unsigned short* qrow = Qs + row * 64;
    const float* pr = ppS + r * 64;
    float s = 0.f;
#pragma unroll
    for (int d8 = 0; d8 < 8; ++d8) {
      short8 qv = *(const short8*)(qrow + d8 * 8);
#pragma unroll
      for (int j = 0; j < 8; ++j)
        s += bf2f((unsigned short)qv[j]) * pr[d8 * 8 + j];
    }
    biasS[row * 12 + r] = s;
  }
  __syncthreads();

  // Q fragments (B-operand): lane holds Q[q = wl*16+lr][d = c*32+lg*8+j]
  const int qrowL = half * 64 + wl * 16 + lr;  // local Qs/bias row
  short8 aq[2];
#pragma unroll
  for (int c = 0; c < 2; ++c)
    aq[c] = *(const short8*)(Qs + qrowL * 64 + c * 32 + lg * 8);

  const int q_glob = qbase + wl * 16 + lr;
  const float b8 = biasS[qrowL * 12 + 8];  // far-distance bucket bias

  float m_run = -1e30f, l_run = 0.f;
  floatx4 o[4] = {};

  for (int kt = 0; kt <= qtB; ++kt) {
    const int kbase = kt * 64;
    const int cur = kt & 1;
    if (kt < qtB) stage_kv(kbase + 64, cur ^ 1);  // prefetch next (all waves)

    if (kt <= myQt) {
      // S^T = K @ Q^T : lane holds S[k = kf*16+lg*4+r][q = wl*16+lr]
      floatx4 sa[4] = {};
      __builtin_amdgcn_s_setprio(1);
#pragma unroll
      for (int kf = 0; kf < 4; ++kf)
#pragma unroll
        for (int c = 0; c < 2; ++c) {
          int row = kf * 16 + lr;
          short8 ak = *(const short8*)(Ks[cur] + row * 64 +
                                       (((c * 4 + lg) ^ (lr & 7)) * 8));
          sa[kf] = __builtin_amdgcn_mfma_f32_16x16x32_bf16(ak, aq[c], sa[kf],
                                                           0, 0, 0);
        }
      __builtin_amdgcn_s_setprio(0);

      // bias + causal mask
      float bext;
      if (qbase + wl * 16 >= kbase + 67) {  // whole wave sub-tile at dist >= 4
        bext = b8;                          // folded into exp arg below
      } else {
        bext = 0.f;
#pragma unroll
        for (int kf = 0; kf < 4; ++kf)
#pragma unroll
          for (int r = 0; r < 4; ++r) {
            int dq = q_glob - (kbase + kf * 16 + lg * 4 + r);
            if (dq < 0)
              sa[kf][r] = -1e30f;
            else
              sa[kf][r] += biasS[qrowL * 12 + (dq > 4 ? 8 : dq + 4)];
          }
      }

      // online softmax with defer-max (THR=8)
      float mx = -1e30f;
#pragma unroll
      for (int kf = 0; kf < 4; ++kf)
#pragma unroll
        for (int r = 0; r < 4; ++r) mx = fmaxf(mx, sa[kf][r]);
      mx += bext;
      mx = fmaxf(mx, __shfl_xor(mx, 16, 64));
      mx = fmaxf(mx, __shfl_xor(mx, 32, 64));
      if (__any(mx > m_run + 8.f)) {
        float mn = fmaxf(m_run, mx);
        float al = __builtin_amdgcn_exp2f((m_run - mn) * LOG2E);
        m_run = mn;
        l_run *= al;
        float alo[4];
#pragma unroll
        for (int r = 0; r < 4; ++r) alo[r] = __shfl(al, lg * 4 + r, 64);
#pragma unroll
        for (int df = 0; df < 4; ++df)
#pragma unroll
          for (int r = 0; r < 4; ++r) o[df][r] *= alo[r];
      }

      const float c1 = (bext - m_run) * LOG2E;
      float rs = 0.f;
#pragma unroll
      for (int kf = 0; kf < 4; ++kf) {
        float p0 = __builtin_amdgcn_exp2f(fmaf(sa[kf][0], LOG2E, c1));
        float p1 = __builtin_amdgcn_exp2f(fmaf(sa[kf][1], LOG2E, c1));
        float p2 = __builtin_amdgcn_exp2f(fmaf(sa[kf][2], LOG2E, c1));
        float p3 = __builtin_amdgcn_exp2f(fmaf(sa[kf][3], LOG2E, c1));
        rs += (p0 + p1) + (p2 + p3);
        uint2v pk;
        pk[0] = cvt_pk_bf16(p0, p1);
        pk[1] = cvt_pk_bf16(p2, p3);
        int phys = (kf * 2 + (lg >> 1)) ^ (lr & 7);
        *(uint2v*)(Ps[w] + lr * 64 + phys * 8 + (lg & 1) * 4) = pk;
      }
      rs += __shfl_xor(rs, 16, 64);
      rs += __shfl_xor(rs, 32, 64);
      l_run += rs;

      // O += P @ V
      __builtin_amdgcn_s_setprio(1);
#pragma unroll
      for (int c = 0; c < 2; ++c) {
        short8 pa = *(const short8*)(Ps[w] + lr * 64 +
                                     (((c * 4 + lg) ^ (lr & 7)) * 8));
#pragma unroll
        for (int df = 0; df < 4; ++df) {
          int row = df * 16 + lr;
          short8 bv = *(const short8*)(Vs[cur] + row * 64 +
                                       (((c * 4 + lg) ^ (lr & 7)) * 8));
          o[df] = __builtin_amdgcn_mfma_f32_16x16x32_bf16(pa, bv, o[df],
                                                          0, 0, 0);
        }
      }
      __builtin_amdgcn_s_setprio(0);
    }
    __syncthreads();  // drains prefetch vmem + guards buffer swap
  }

  // epilogue: lane holds O[q = wl*16+lg*4+r][d = df*16+lr]
  float rl[4];
#pragma unroll
  for (int r = 0; r < 4; ++r)
    rl[r] = __builtin_amdgcn_rcpf(__shfl(l_run, lg * 4 + r, 64));
  const size_t outRow0 = (size_t)b * 2048 + qbase + wl * 16 + lg * 4;
#pragma unroll
  for (int df = 0; df < 4; ++df)
#pragma unroll
    for (int r = 0; r < 4; ++r) {
      float v = o[df][r] * rl[r];
      ao[(outRow0 + r) * 1024 + h * 64 + df * 16 + lr] = f2bf(v);
    }
}

// --------------------------------- launcher ---------------------------------
extern "C" void kernel_launch(void* const* d_in, const int* in_sizes, int n_in,
                              void* d_out, int out_size, void* d_ws,
                              size_t ws_size, hipStream_t stream) {
  const float* k_in = (const float*)d_in[0];  // k == v == q (same x tensor)
  const float* Wk = (const float*)d_in[3];
  const float* Wv = (const float*)d_in[4];
  const float* Wq = (const float*)d_in[5];
  const float* Wo = (const float*)d_in[6];
  const float* pp = (const float*)d_in[7];

  const size_t NX = 4096u * 1024u;
  const size_t NW = 1024u * 1024u;
  unsigned short* ws = (unsigned short*)d_ws;
  unsigned short* xbf = ws;
  unsigned short* wkb = xbf + NX;
  unsigned short* wvb = wkb + NW;
  unsigned short* wqb = wvb + NW;
  unsigned short* wob = wqb + NW;
  unsigned short* khb = wob + NW;
  unsigned short* vtb = khb + NX;
  unsigned short* qhb = vtb + NX;
  unsigned short* aob = qhb + NX;

  (void)in_sizes; (void)n_in; (void)out_size; (void)ws_size;

  f2bf_kern<<<dim3(4096), dim3(256), 0, stream>>>(k_in, xbf, (int)(NX / 4));
  f2bfW_kern<<<dim3(1024, 4), dim3(256), 0, stream>>>(
      Wk, wkb, Wv, wvb, Wq, wqb, Wo, wob);

  proj3_kern<<<dim3(8, 32, 3), dim3(256), 0, stream>>>(
      xbf, wkb, khb, wqb, qhb, wvb, vtb);

  attn_kern<<<dim3(16, 16, 2), dim3(512), 0, stream>>>(qhb, khb, vtb, pp, aob);

  gemm_out_kern<<<dim3(8, 32), dim3(256), 0, stream>>>(aob, wob, (float*)d_out);
}

// Round 6
// 123.551 us; speedup vs baseline: 2.0824x; 1.0883x over previous
//
#include <hip/hip_runtime.h>

// ---------------------------------------------------------------------------
// MultiheadAttention (B=2, S=2048, E=1024, H=16, D=64, MAX_DIST=4, causal)
//   1. f2bf converts (x once; 4 weights fused)
//   2. proj3: kh=[bs][e], qh=[bs][e] (*0.125), vt=[e][bs]
//   3. flash attention v5: SPLIT-K uniform work units (<=16 k-tiles), 4-wave
//      blocks, LPT launch order, 3 blocks/CU, partial O + combine for long
//      q-tiles. Swapped QK^T, XOR-swizzle, dbuf K/V, defer-max, cvt_pk.
//   4. combine partials -> ao
//   5. out = ao @ Wo^T -> fp32
// ---------------------------------------------------------------------------

using short8  = __attribute__((ext_vector_type(8))) short;
using floatx4 = __attribute__((ext_vector_type(4))) float;
using float4v = __attribute__((ext_vector_type(4))) float;
using ushort4v = __attribute__((ext_vector_type(4))) unsigned short;
using uint2v  = __attribute__((ext_vector_type(2))) unsigned int;

#define LOG2E 1.4426950408889634f

__device__ __forceinline__ unsigned short f2bf(float f) {
  unsigned u = __float_as_uint(f);
  return (unsigned short)((u + 0x7FFFu + ((u >> 16) & 1u)) >> 16);  // RNE
}
__device__ __forceinline__ float bf2f(unsigned short s) {
  return __uint_as_float(((unsigned)s) << 16);
}
__device__ __forceinline__ unsigned cvt_pk_bf16(float lo, float hi) {
  unsigned r;
  asm("v_cvt_pk_bf16_f32 %0, %1, %2" : "=v"(r) : "v"(lo), "v"(hi));
  return r;
}
__device__ __forceinline__ void gload_lds16(const void* g, void* l) {
  __builtin_amdgcn_global_load_lds(
      (const __attribute__((address_space(1))) unsigned int*)g,
      (__attribute__((address_space(3))) unsigned int*)l, 16, 0, 0);
}

// --------------------------- fp32 -> bf16 convert ---------------------------
__global__ void f2bf_kern(const float* __restrict__ in,
                          unsigned short* __restrict__ out, int n4) {
  int i = blockIdx.x * 256 + threadIdx.x;
  if (i >= n4) return;
  float4v v = ((const float4v*)in)[i];
  ushort4v o;
  o[0] = f2bf(v[0]); o[1] = f2bf(v[1]); o[2] = f2bf(v[2]); o[3] = f2bf(v[3]);
  ((ushort4v*)out)[i] = o;
}

__global__ void f2bfW_kern(const float* __restrict__ w0, unsigned short* o0,
                           const float* __restrict__ w1, unsigned short* o1,
                           const float* __restrict__ w2, unsigned short* o2,
                           const float* __restrict__ w3, unsigned short* o3) {
  int i = blockIdx.x * 256 + threadIdx.x;
  const float* in;
  unsigned short* out;
  switch (blockIdx.y) {
    case 0: in = w0; out = o0; break;
    case 1: in = w1; out = o1; break;
    case 2: in = w2; out = o2; break;
    default: in = w3; out = o3; break;
  }
  float4v v = ((const float4v*)in)[i];
  ushort4v o;
  o[0] = f2bf(v[0]); o[1] = f2bf(v[1]); o[2] = f2bf(v[2]); o[3] = f2bf(v[3]);
  ((ushort4v*)out)[i] = o;
}

// ------------------------------ GEMM core (NT) ------------------------------
__device__ __forceinline__ void gemm_core(
    const unsigned short* __restrict__ A, const unsigned short* __restrict__ B,
    void* __restrict__ Cv, int N, int K, int mBase, int nBase, float alpha,
    bool outbf, unsigned short* As, unsigned short* Bs) {
  const int tid = threadIdx.x;
  const int lane = tid & 63;
  const int w = tid >> 6;
  const int wr = w >> 1, wc = w & 1;
  const int lr = lane & 15, lg = lane >> 4;

  floatx4 acc[4][4] = {};

  for (int k0 = 0; k0 < K; k0 += 32) {
#pragma unroll
    for (int i = 0; i < 2; ++i) {
      int idx = i * 256 + tid;
      int row = idx >> 2, c8 = (idx & 3) * 8;
      gload_lds16(A + (size_t)(mBase + row) * K + (k0 + c8), As + idx * 8);
      gload_lds16(B + (size_t)(nBase + row) * K + (k0 + c8), Bs + idx * 8);
    }
    __syncthreads();
    short8 af[4], bfr[4];
#pragma unroll
    for (int mf = 0; mf < 4; ++mf)
      af[mf] = *(const short8*)(As + (wr * 64 + mf * 16 + lr) * 32 + lg * 8);
#pragma unroll
    for (int nf = 0; nf < 4; ++nf)
      bfr[nf] = *(const short8*)(Bs + (wc * 64 + nf * 16 + lr) * 32 + lg * 8);
#pragma unroll
    for (int mf = 0; mf < 4; ++mf)
#pragma unroll
      for (int nf = 0; nf < 4; ++nf)
        acc[mf][nf] = __builtin_amdgcn_mfma_f32_16x16x32_bf16(
            af[mf], bfr[nf], acc[mf][nf], 0, 0, 0);
    __syncthreads();
  }

#pragma unroll
  for (int mf = 0; mf < 4; ++mf)
#pragma unroll
    for (int nf = 0; nf < 4; ++nf)
#pragma unroll
      for (int r = 0; r < 4; ++r) {
        size_t row = (size_t)mBase + wr * 64 + mf * 16 + lg * 4 + r;
        size_t col = (size_t)nBase + wc * 64 + nf * 16 + lr;
        float v = acc[mf][nf][r] * alpha;
        if (outbf)
          ((unsigned short*)Cv)[row * (size_t)N + col] = f2bf(v);
        else
          ((float*)Cv)[row * (size_t)N + col] = v;
      }
}

__global__ __launch_bounds__(256, 2) void proj3_kern(
    const unsigned short* __restrict__ xbf, const unsigned short* __restrict__ wkb,
    unsigned short* __restrict__ khb,
    const unsigned short* __restrict__ wqb, unsigned short* __restrict__ qhb,
    const unsigned short* __restrict__ wvb, unsigned short* __restrict__ vtb) {
  __shared__ alignas(16) unsigned short As[128 * 32];
  __shared__ alignas(16) unsigned short Bs[128 * 32];
  int z = blockIdx.z;
  if (z == 0)
    gemm_core(xbf, wkb, khb, 1024, 1024, blockIdx.y * 128, blockIdx.x * 128,
              1.0f, true, As, Bs);
  else if (z == 1)
    gemm_core(xbf, wqb, qhb, 1024, 1024, blockIdx.y * 128, blockIdx.x * 128,
              0.125f, true, As, Bs);
  else
    gemm_core(wvb, xbf, vtb, 4096, 1024, blockIdx.x * 128, blockIdx.y * 128,
              1.0f, true, As, Bs);
}

__global__ __launch_bounds__(256, 2) void gemm_out_kern(
    const unsigned short* __restrict__ A, const unsigned short* __restrict__ B,
    float* __restrict__ C) {
  __shared__ alignas(16) unsigned short As[128 * 32];
  __shared__ alignas(16) unsigned short Bs[128 * 32];
  gemm_core(A, B, C, 1024, 1024, blockIdx.y * 128, blockIdx.x * 128, 1.0f,
            false, As, Bs);
}

// ---------------------------- flash attention v5 ----------------------------
// Split-K: grid (32 hb, 48 units). Unit u (sorted desc by length for LPT):
//   u=0:        qt=15, kt 0..15          (16 steps, direct)
//   u=1..16:    qt=15+u, kt 0..15        (16 steps, partial chunk 0)
//   u=17:       qt=31, kt 16..31         (16 steps, partial chunk 1)
//   u>=18: p=(u-18)>>1; even: qt=14-p full (15-p steps, direct)
//                       odd:  qt=30-p, kt 16..qt (15-p steps, partial chunk 1)
// 4 waves, each owns 16 q-rows. LDS 43KB -> 3 blocks/CU. Qs region becomes
// K-buf-1 after prologue; ppS overlays Ps.
__global__ __launch_bounds__(256, 3) void attn_kern(
    const unsigned short* __restrict__ qh,   // [4096][1024], pre-scaled
    const unsigned short* __restrict__ kh,   // [4096][1024]
    const unsigned short* __restrict__ vt,   // [1024][4096]
    const float* __restrict__ pp,            // [64][9]
    unsigned short* __restrict__ ao,         // [4096][1024]
    unsigned short* __restrict__ opart,      // [1024][64][64] bf16 unnorm
    float* __restrict__ mbuf,                // [1024][64]
    float* __restrict__ lbuf) {              // [1024][64]
  __shared__ alignas(16) char smem[44032];
  unsigned short* Qs  = (unsigned short*)smem;            // 8K; later Ks[1]
  unsigned short* Vs1 = (unsigned short*)(smem + 8192);   // 8K
  unsigned short* Ks0 = (unsigned short*)(smem + 16384);  // 8K
  unsigned short* Vs0 = (unsigned short*)(smem + 24576);  // 8K
  unsigned short* Ps  = (unsigned short*)(smem + 32768);  // 8K (4 waves x 2K)
  float* biasS = (float*)(smem + 40960);                  // 64*12*4 = 3K
  float* ppS   = (float*)(smem + 32768);                  // overlays Ps

  const int tid = threadIdx.x;
  const int lane = tid & 63;
  const int w = tid >> 6;   // 0..3, owns q rows w*16..w*16+15
  const int lr = lane & 15, lg = lane >> 4;
  const int hb = blockIdx.x;
  const int h = hb & 15, b = hb >> 4;
  const int u = blockIdx.y;

  int qt, k0, k1;
  if (u == 0)       { qt = 15;     k0 = 0;  k1 = 16; }
  else if (u <= 16) { qt = 15 + u; k0 = 0;  k1 = 16; }
  else if (u == 17) { qt = 31;     k0 = 16; k1 = 32; }
  else {
    int p = (u - 18) >> 1;
    if (((u - 18) & 1) == 0) { qt = 14 - p; k0 = 0;  k1 = qt + 1; }
    else                     { qt = 30 - p; k0 = 16; k1 = qt + 1; }
  }
  const bool partial = (qt >= 16);
  const int qbase = qt * 64;
  const size_t bsQ = (size_t)b * 2048 + qbase;

  const unsigned short* khB = kh + ((size_t)b * 2048) * 1024 + h * 64;
  const unsigned short* vtB = vt + ((size_t)h * 64) * 4096 + b * 2048;

  auto stage_kv = [&](int kbase, unsigned short* Kd, unsigned short* Vd) {
#pragma unroll
    for (int i = 0; i < 2; ++i) {
      int idx = i * 256 + tid;
      int row = idx >> 3, pc = idx & 7;
      int cl = pc ^ (row & 7);  // pre-swizzled global source
      gload_lds16(khB + ((size_t)(kbase + row) << 10) + cl * 8, Kd + idx * 8);
      gload_lds16(vtB + ((size_t)row << 12) + kbase + cl * 8, Vd + idx * 8);
    }
  };

  // prologue: stage Q (linear), pp table, first K/V tile
#pragma unroll
  for (int i = 0; i < 2; ++i) {
    int idx = i * 256 + tid;
    int row = idx >> 3, c8 = (idx & 7) * 8;
    gload_lds16(qh + (bsQ + row) * 1024 + h * 64 + c8, Qs + idx * 8);
  }
  for (int idx = tid; idx < 576; idx += 256) {
    int r = idx >> 6, d = idx & 63;
    ppS[r * 64 + d] = pp[d * 9 + r];
  }
  stage_kv(k0 * 64, Ks0, Vs0);
  __syncthreads();

  // Q fragments (B-operand): lane holds Q[q = w*16+lr][d = c*32+lg*8+j]
  const int qrowL = w * 16 + lr;
  short8 aq[2];
#pragma unroll
  for (int c = 0; c < 2; ++c)
    aq[c] = *(const short8*)(Qs + qrowL * 64 + c * 32 + lg * 8);

  // rel-pos bias: biasS[row][r] = sum_d qh_scaled[row][d] * p[d][r]
  for (int idx = tid; idx < 576; idx += 256) {
    int row = idx / 9, r = idx - row * 9;
    const unsigned short* qrow = Qs + row * 64;
    const float* pr = ppS + r * 64;
    float s = 0.f;
#pragma unroll
    for (int d8 = 0; d8 < 8; ++d8) {
      short8 qv = *(const short8*)(qrow + d8 * 8);
#pragma unroll
      for (int j = 0; j < 8; ++j)
        s += bf2f((unsigned short)qv[j]) * pr[d8 * 8 + j];
    }
    biasS[row * 12 + r] = s;
  }
  __syncthreads();  // after this, Qs/ppS regions are dead -> buf1 targets

  const int q_glob = qbase + w * 16 + lr;
  const float b8 = biasS[qrowL * 12 + 8];
  unsigned short* Pw = Ps + w * 1024;

  float m_run = -1e30f, l_run = 0.f;
  floatx4 o[4] = {};

  for (int kt = k0; kt < k1; ++kt) {
    const int kbase = kt * 64;
    const int cur = (kt - k0) & 1;
    unsigned short* Kc = cur ? Qs : Ks0;
    unsigned short* Vc = cur ? Vs1 : Vs0;
    if (kt + 1 < k1)
      stage_kv(kbase + 64, cur ? Ks0 : Qs, cur ? Vs0 : Vs1);  // prefetch

    // S^T = K @ Q^T : lane holds S[k = kf*16+lg*4+r][q = w*16+lr]
    floatx4 sa[4] = {};
    __builtin_amdgcn_s_setprio(1);
#pragma unroll
    for (int kf = 0; kf < 4; ++kf)
#pragma unroll
      for (int c = 0; c < 2; ++c) {
        int row = kf * 16 + lr;
        short8 ak = *(const short8*)(Kc + row * 64 +
                                     (((c * 4 + lg) ^ (lr & 7)) * 8));
        sa[kf] = __builtin_amdgcn_mfma_f32_16x16x32_bf16(ak, aq[c], sa[kf],
                                                         0, 0, 0);
      }
    __builtin_amdgcn_s_setprio(0);

    // bias + causal mask
    float bext;
    if (qbase + w * 16 >= kbase + 67) {  // whole wave sub-tile at dist >= 4
      bext = b8;                         // folded into exp arg below
    } else {
      bext = 0.f;
#pragma unroll
      for (int kf = 0; kf < 4; ++kf)
#pragma unroll
        for (int r = 0; r < 4; ++r) {
          int dq = q_glob - (kbase + kf * 16 + lg * 4 + r);
          if (dq < 0)
            sa[kf][r] = -1e30f;
          else
            sa[kf][r] += biasS[qrowL * 12 + (dq > 4 ? 8 : dq + 4)];
        }
    }

    // online softmax with defer-max (THR=8)
    float mx = -1e30f;
#pragma unroll
    for (int kf = 0; kf < 4; ++kf)
#pragma unroll
      for (int r = 0; r < 4; ++r) mx = fmaxf(mx, sa[kf][r]);
    mx += bext;
    mx = fmaxf(mx, __shfl_xor(mx, 16, 64));
    mx = fmaxf(mx, __shfl_xor(mx, 32, 64));
    if (__any(mx > m_run + 8.f)) {
      float mn = fmaxf(m_run, mx);
      float al = __builtin_amdgcn_exp2f((m_run - mn) * LOG2E);
      m_run = mn;
      l_run *= al;
      float alo[4];
#pragma unroll
      for (int r = 0; r < 4; ++r) alo[r] = __shfl(al, lg * 4 + r, 64);
#pragma unroll
      for (int df = 0; df < 4; ++df)
#pragma unroll
        for (int r = 0; r < 4; ++r) o[df][r] *= alo[r];
    }

    const float c1 = (bext - m_run) * LOG2E;
    float rs = 0.f;
#pragma unroll
    for (int kf = 0; kf < 4; ++kf) {
      float p0 = __builtin_amdgcn_exp2f(fmaf(sa[kf][0], LOG2E, c1));
      float p1 = __builtin_amdgcn_exp2f(fmaf(sa[kf][1], LOG2E, c1));
      float p2 = __builtin_amdgcn_exp2f(fmaf(sa[kf][2], LOG2E, c1));
      float p3 = __builtin_amdgcn_exp2f(fmaf(sa[kf][3], LOG2E, c1));
      rs += (p0 + p1) + (p2 + p3);
      uint2v pk;
      pk[0] = cvt_pk_bf16(p0, p1);
      pk[1] = cvt_pk_bf16(p2, p3);
      int phys = (kf * 2 + (lg >> 1)) ^ (lr & 7);
      *(uint2v*)(Pw + lr * 64 + phys * 8 + (lg & 1) * 4) = pk;
    }
    rs += __shfl_xor(rs, 16, 64);
    rs += __shfl_xor(rs, 32, 64);
    l_run += rs;

    // O += P @ V
    __builtin_amdgcn_s_setprio(1);
#pragma unroll
    for (int c = 0; c < 2; ++c) {
      short8 pa = *(const short8*)(Pw + lr * 64 +
                                   (((c * 4 + lg) ^ (lr & 7)) * 8));
#pragma unroll
      for (int df = 0; df < 4; ++df) {
        int row = df * 16 + lr;
        short8 bv = *(const short8*)(Vc + row * 64 +
                                     (((c * 4 + lg) ^ (lr & 7)) * 8));
        o[df] = __builtin_amdgcn_mfma_f32_16x16x32_bf16(pa, bv, o[df],
                                                        0, 0, 0);
      }
    }
    __builtin_amdgcn_s_setprio(0);
    __syncthreads();  // drains prefetch vmem + guards buffer swap
  }

  // epilogue: lane holds O[q = w*16+lg*4+r][d = df*16+lr]
  if (!partial) {
    float rl[4];
#pragma unroll
    for (int r = 0; r < 4; ++r)
      rl[r] = __builtin_amdgcn_rcpf(__shfl(l_run, lg * 4 + r, 64));
    const size_t outRow0 = bsQ + w * 16 + lg * 4;
#pragma unroll
    for (int df = 0; df < 4; ++df)
#pragma unroll
      for (int r = 0; r < 4; ++r)
        ao[(outRow0 + r) * 1024 + h * 64 + df * 16 + lr] =
            f2bf(o[df][r] * rl[r]);
  } else {
    const int pid = (hb * 16 + (qt - 16)) * 2 + (k0 == 16 ? 1 : 0);
    unsigned short* op = opart + (size_t)pid * 4096;
#pragma unroll
    for (int df = 0; df < 4; ++df)
#pragma unroll
      for (int r = 0; r < 4; ++r)
        op[(w * 16 + lg * 4 + r) * 64 + df * 16 + lr] = f2bf(o[df][r]);
    if (lg == 0) {
      mbuf[pid * 64 + w * 16 + lr] = m_run;
      lbuf[pid * 64 + w * 16 + lr] = l_run;
    }
  }
}

// ------------------------------ combine partials -----------------------------
__global__ void combine_kern(const unsigned short* __restrict__ opart,
                             const float* __restrict__ mbuf,
                             const float* __restrict__ lbuf,
                             unsigned short* __restrict__ ao) {
  const int t = blockIdx.x;         // 0..511
  const int hb = t >> 4;
  const int qtl = t & 15;
  const int qt = 16 + qtl;
  const int b = hb >> 4, h = hb & 15;
  const int pid0 = (hb * 16 + qtl) * 2, pid1 = pid0 + 1;
  const int row = threadIdx.x >> 2;
  const int colg = (threadIdx.x & 3) * 16;

  float m1 = mbuf[pid0 * 64 + row], m2 = mbuf[pid1 * 64 + row];
  float l1 = lbuf[pid0 * 64 + row], l2 = lbuf[pid1 * 64 + row];
  float m = fmaxf(m1, m2);
  float s1 = __builtin_amdgcn_exp2f((m1 - m) * LOG2E);
  float s2 = __builtin_amdgcn_exp2f((m2 - m) * LOG2E);
  float linv = 1.f / fmaf(l1, s1, l2 * s2);
  s1 *= linv; s2 *= linv;

  const unsigned short* O1 = opart + (size_t)pid0 * 4096 + row * 64 + colg;
  const unsigned short* O2 = opart + (size_t)pid1 * 4096 + row * 64 + colg;
  unsigned short* dst =
      ao + ((size_t)b * 2048 + qt * 64 + row) * 1024 + h * 64 + colg;
#pragma unroll
  for (int i = 0; i < 2; ++i) {
    short8 a = *(const short8*)(O1 + i * 8);
    short8 c = *(const short8*)(O2 + i * 8);
    short8 ov;
#pragma unroll
    for (int j = 0; j < 8; ++j)
      ov[j] = (short)f2bf(fmaf(bf2f((unsigned short)a[j]), s1,
                               bf2f((unsigned short)c[j]) * s2));
    *(short8*)(dst + i * 8) = ov;
  }
}

// --------------------------------- launcher ---------------------------------
extern "C" void kernel_launch(void* const* d_in, const int* in_sizes, int n_in,
                              void* d_out, int out_size, void* d_ws,
                              size_t ws_size, hipStream_t stream) {
  const float* k_in = (const float*)d_in[0];  // k == v == q (same x tensor)
  const float* Wk = (const float*)d_in[3];
  const float* Wv = (const float*)d_in[4];
  const float* Wq = (const float*)d_in[5];
  const float* Wo = (const float*)d_in[6];
  const float* pp = (const float*)d_in[7];

  const size_t NX = 4096u * 1024u;
  const size_t NW = 1024u * 1024u;
  unsigned short* ws = (unsigned short*)d_ws;
  unsigned short* xbf = ws;
  unsigned short* wkb = xbf + NX;
  unsigned short* wvb = wkb + NW;
  unsigned short* wqb = wvb + NW;
  unsigned short* wob = wqb + NW;
  unsigned short* khb = wob + NW;
  unsigned short* vtb = khb + NX;
  unsigned short* qhb = vtb + NX;
  unsigned short* aob = qhb + NX;
  unsigned short* opart = aob + NX;          // 1024 tiles x 4096 bf16 = 8 MB
  float* mbuf = (float*)(opart + NX);        // 1024*64 f32
  float* lbuf = mbuf + 1024 * 64;

  (void)in_sizes; (void)n_in; (void)out_size; (void)ws_size;

  f2bf_kern<<<dim3(4096), dim3(256), 0, stream>>>(k_in, xbf, (int)(NX / 4));
  f2bfW_kern<<<dim3(1024, 4), dim3(256), 0, stream>>>(
      Wk, wkb, Wv, wvb, Wq, wqb, Wo, wob);

  proj3_kern<<<dim3(8, 32, 3), dim3(256), 0, stream>>>(
      xbf, wkb, khb, wqb, qhb, wvb, vtb);

  attn_kern<<<dim3(32, 48), dim3(256), 0, stream>>>(qhb, khb, vtb, pp, aob,
                                                    opart, mbuf, lbuf);
  combine_kern<<<dim3(512), dim3(256), 0, stream>>>(opart, mbuf, lbuf, aob);

  gemm_out_kern<<<dim3(8, 32), dim3(256), 0, stream>>>(aob, wob, (float*)d_out);
}